// Round 11
// baseline (1043.496 us; speedup 1.0000x reference)
//
#include <hip/hip_runtime.h>

#define DM     1024
#define DFF    4096
#define NE     8
#define TT     8192
#define CAP    8192
#define RTOK   32
#define MAXRA  17664

typedef __bf16 bf16x8 __attribute__((ext_vector_type(8)));
typedef float  f32x4  __attribute__((ext_vector_type(4)));
typedef unsigned short u16;
typedef unsigned int   u32;

__device__ __forceinline__ u16 f2bf(float f) {
    u32 u = __builtin_bit_cast(u32, f);
    u += 0x7fffu + ((u >> 16) & 1u);   // round-to-nearest-even
    return (u16)(u >> 16);
}

__device__ __forceinline__ float bf2f(u16 h) {
    u32 u = ((u32)h) << 16;
    return __builtin_bit_cast(float, u);
}

__device__ __forceinline__ void gload_lds16(const void* g, void* l) {
    __builtin_amdgcn_global_load_lds(
        (const __attribute__((address_space(1))) void*)g,
        (__attribute__((address_space(3))) void*)l,
        16, 0, 0);
}

// ---------------- router: block-aggregated top-2 routing ----------------
__global__ __launch_bounds__(256) void router_k(
    const float* __restrict__ x, const float* __restrict__ Wr, const float* __restrict__ br,
    int* __restrict__ expert_count, float* __restrict__ prob_sum,
    int* __restrict__ list_token, float* __restrict__ list_w,
    int* __restrict__ tok_e, int* __restrict__ tok_q, float* __restrict__ tok_w)
{
    __shared__ float wrT[NE][DM];
    __shared__ float ps[NE];
    __shared__ int   lcount[NE];
    __shared__ int   lbase[NE];
    __shared__ int   lexp[RTOK * 2];
    __shared__ float lw[RTOK * 2];
    __shared__ int   lslot[RTOK * 2];

    int tid = threadIdx.x;
    if (tid < NE) { ps[tid] = 0.f; lcount[tid] = 0; }
#pragma unroll
    for (int it = 0; it < 8; ++it) {
        int f = tid * 4 + it * 1024;
        float4 v = *reinterpret_cast<const float4*>(Wr + f);
        int e0 = f & 7, k = f >> 3;
        wrT[e0][k] = v.x; wrT[e0 + 1][k] = v.y; wrT[e0 + 2][k] = v.z; wrT[e0 + 3][k] = v.w;
    }
    __syncthreads();

    int w = tid >> 6, l = tid & 63;
    for (int j = 0; j < RTOK / 4; ++j) {
        int ti = w * (RTOK / 4) + j;
        int token = blockIdx.x * RTOK + ti;
        const float* xr = x + (size_t)token * DM;
        float acc[NE];
#pragma unroll
        for (int e = 0; e < NE; ++e) acc[e] = 0.f;
#pragma unroll
        for (int i = 0; i < 4; ++i) {
            float4 xv = *reinterpret_cast<const float4*>(xr + i * 256 + l * 4);
#pragma unroll
            for (int e = 0; e < NE; ++e) {
                float4 wv = *reinterpret_cast<const float4*>(&wrT[e][i * 256 + l * 4]);
                acc[e] += xv.x * wv.x + xv.y * wv.y + xv.z * wv.z + xv.w * wv.w;
            }
        }
#pragma unroll
        for (int off = 32; off >= 1; off >>= 1) {
#pragma unroll
            for (int e = 0; e < NE; ++e) acc[e] += __shfl_xor(acc[e], off);
        }
        if (l == 0) {
            float li[NE], m = -1e30f;
#pragma unroll
            for (int e = 0; e < NE; ++e) { li[e] = (acc[e] + br[e]) * (1.0f / 0.7f); m = fmaxf(m, li[e]); }
            float p[NE], s = 0.f;
#pragma unroll
            for (int e = 0; e < NE; ++e) { p[e] = __expf(li[e] - m); s += p[e]; }
            float inv = 1.f / s;
#pragma unroll
            for (int e = 0; e < NE; ++e) { p[e] *= inv; atomicAdd(&ps[e], p[e]); }
            float v1 = -1.f, v2 = -1.f; int e1 = 0, e2 = 0;
#pragma unroll
            for (int e = 0; e < NE; ++e) {   // ascending scan: ties keep lower index (top_k semantics)
                float pe = p[e];
                if (pe > v1)      { v2 = v1; e2 = e1; v1 = pe; e1 = e; }
                else if (pe > v2) { v2 = pe; e2 = e; }
            }
            float denom = v1 + v2 + 1e-6f;
            lexp[2 * ti]     = e1; lw[2 * ti]     = v1 / denom; lslot[2 * ti]     = atomicAdd(&lcount[e1], 1);
            lexp[2 * ti + 1] = e2; lw[2 * ti + 1] = v2 / denom; lslot[2 * ti + 1] = atomicAdd(&lcount[e2], 1);
        }
    }
    __syncthreads();
    if (tid < NE) {
        lbase[tid] = atomicAdd(&expert_count[tid], lcount[tid]);
        atomicAdd(&prob_sum[tid], ps[tid]);
    }
    __syncthreads();
    if (tid < RTOK * 2) {
        int e = lexp[tid];
        int q = lbase[e] + lslot[tid];
        int token = blockIdx.x * RTOK + (tid >> 1);
        list_token[e * CAP + q] = token;
        list_w[e * CAP + q] = lw[tid];
        int slot = token * 2 + (tid & 1);
        tok_e[slot] = e; tok_q[slot] = q; tok_w[slot] = lw[tid];
    }
}

// ---------------- scan: padded offsets (to 128) + aux loss ----------------
__global__ void scan_aux_k(const int* __restrict__ expert_count, const float* __restrict__ prob_sum,
                           int* __restrict__ padded_count, int* __restrict__ poffsets,
                           float* __restrict__ aux_out)
{
    if (threadIdx.x == 0 && blockIdx.x == 0) {
        int off = 0; float aux = 0.f;
        for (int e = 0; e < NE; ++e) {
            int c = expert_count[e];
            int pc = (c + 127) / 128 * 128;
            poffsets[e] = off; padded_count[e] = pc; off += pc;
            aux += ((float)c / (float)TT) * (prob_sum[e] / (float)TT);
        }
        aux_out[0] = aux * (float)NE;
    }
}

// ---------------- gather routed x rows -> bf16 Xg ----------------
__global__ __launch_bounds__(256) void gather_k(
    const float* __restrict__ x, const int* __restrict__ list_token,
    const int* __restrict__ expert_count, const int* __restrict__ padded_count,
    const int* __restrict__ poffsets, u16* __restrict__ Xg)
{
    int e = blockIdx.y;
    int p0 = blockIdx.x * 8;
    if (p0 >= padded_count[e]) return;
    int tid = threadIdx.x;
    int rr = tid >> 5, cl = tid & 31;
    int p = p0 + rr;
    int g = poffsets[e] + p;
    u16* dst = Xg + (size_t)g * DM;
    bool valid = p < expert_count[e];
    int tok = valid ? list_token[e * CAP + p] : 0;
    const float* src = x + (size_t)tok * DM;
#pragma unroll
    for (int i = 0; i < 4; ++i) {
        int c0 = cl * 8 + i * 256;
        uint4 v;
        if (valid) {
            float4 f0 = *reinterpret_cast<const float4*>(src + c0);
            float4 f1 = *reinterpret_cast<const float4*>(src + c0 + 4);
            v.x = f2bf(f0.x) | ((u32)f2bf(f0.y) << 16);
            v.y = f2bf(f0.z) | ((u32)f2bf(f0.w) << 16);
            v.z = f2bf(f1.x) | ((u32)f2bf(f1.y) << 16);
            v.w = f2bf(f1.z) | ((u32)f2bf(f1.w) << 16);
        } else {
            v.x = 0; v.y = 0; v.z = 0; v.w = 0;
        }
        *reinterpret_cast<uint4*>(dst + c0) = v;
    }
}

// ---------------- transpose + fp32->bf16: src[e][k*rs + j] -> dst[e][j*Ktot + k] ----------------
__global__ __launch_bounds__(256) void convt_k(
    const float* __restrict__ src, u16* __restrict__ dst, int rs, int Ktot, long dstEStride)
{
    __shared__ float tile[64][65];
    int e = blockIdx.z;
    int k0 = blockIdx.x * 64, j0 = blockIdx.y * 64;
    const float* s = src + (size_t)e * 4194304;
    int tid = threadIdx.x;
    {
        int jj = (tid & 15) * 4, kb = tid >> 4;
#pragma unroll
        for (int i = 0; i < 4; ++i) {
            int k = kb + i * 16;
            float4 v = *reinterpret_cast<const float4*>(s + (size_t)(k0 + k) * rs + j0 + jj);
            tile[k][jj] = v.x; tile[k][jj + 1] = v.y; tile[k][jj + 2] = v.z; tile[k][jj + 3] = v.w;
        }
    }
    __syncthreads();
    {
        int kk = (tid & 15) * 4, jb = tid >> 4;
        u16* d = dst + (size_t)e * dstEStride;
#pragma unroll
        for (int i = 0; i < 4; ++i) {
            int j = jb + i * 16;
            uint2 q;
            q.x = f2bf(tile[kk][j])     | ((u32)f2bf(tile[kk + 1][j]) << 16);
            q.y = f2bf(tile[kk + 2][j]) | ((u32)f2bf(tile[kk + 3][j]) << 16);
            *reinterpret_cast<uint2*>(d + (size_t)(j0 + j) * Ktot + k0 + kk) = q;
        }
    }
}

// ---------------- PROVEN 128x128 bf16 GEMM mainloop (single-buffer, gload_lds, 256 thr) ----------------
// 16B chunk slot = row*8 + (c8 ^ (row&7)); staged linearly via pre-swizzled global source
// (both-sides involution; 0 bank conflicts measured R2-R10). m97-class structure:
// gemm1 ~762 TF / gemm2 ~653 TF — at this structure's proven shape-ceiling (m102/m112).
__device__ __forceinline__ void stage_tile(const u16* __restrict__ rows, long lda, int kt, char* buf) {
    int tid = threadIdx.x;
    int w = tid >> 6, l = tid & 63;
#pragma unroll
    for (int i = 0; i < 4; ++i) {
        int sbase = i * 256 + w * 64;       // wave-uniform LDS slot base
        int sl = sbase + l;
        int row = sl >> 3;
        int c8 = (sl & 7) ^ (row & 7);
        const u16* src = rows + (size_t)row * lda + kt * 64 + c8 * 8;
        gload_lds16(src, buf + sbase * 16);
    }
}

__device__ __forceinline__ void gemm_main(
    const u16* __restrict__ Arows, long lda,
    const u16* __restrict__ Brows, long ldb,
    int nkt, char* smem, f32x4 acc[4][4])
{
    int tid = threadIdx.x;
    int l = tid & 63, lane16 = l & 15, hi = l >> 4;
    int wm = (tid >> 6) & 1, wn = tid >> 7;

    for (int kt = 0; kt < nkt; ++kt) {
        stage_tile(Arows, lda, kt, smem);
        stage_tile(Brows, ldb, kt, smem + 16384);
        __syncthreads();
        const char* bufA = smem;
        const char* bufB = smem + 16384;
#pragma unroll
        for (int kk = 0; kk < 2; ++kk) {
            bf16x8 af[4], bb[4];
#pragma unroll
            for (int mi = 0; mi < 4; ++mi) {
                int row = wm * 64 + mi * 16 + lane16;
                int ch = (kk * 4 + hi) ^ (row & 7);
                af[mi] = *reinterpret_cast<const bf16x8*>(bufA + (row * 8 + ch) * 16);
            }
#pragma unroll
            for (int ni = 0; ni < 4; ++ni) {
                int row = wn * 64 + ni * 16 + lane16;
                int ch = (kk * 4 + hi) ^ (row & 7);
                bb[ni] = *reinterpret_cast<const bf16x8*>(bufB + (row * 8 + ch) * 16);
            }
#pragma unroll
            for (int mi = 0; mi < 4; ++mi)
#pragma unroll
                for (int ni = 0; ni < 4; ++ni)
                    acc[mi][ni] = __builtin_amdgcn_mfma_f32_16x16x32_bf16(af[mi], bb[ni], acc[mi][ni], 0, 0, 0);
        }
        __syncthreads();
    }
}

// ---------------- GEMM1: H = silu(Xg @ W1c + b1), bf16, N=4096, K=1024 ----------------
// Region-ordered swizzled 1D grid: e (8) x group (8: 8 rb) x rb-in-group (8) x cb (32).
// launch_bounds (256,5): LDS 160/32 = exactly 5 blocks/CU; VGPR 60 <= 102 cap -> no spill.
__global__ __launch_bounds__(256, 5) void gemm1_k(
    const u16* __restrict__ Xg, const u16* __restrict__ W1c, const float* __restrict__ b1,
    const int* __restrict__ padded_count, const int* __restrict__ poffsets,
    u16* __restrict__ H)
{
    __shared__ char smem[32768];
    int n = blockIdx.x;
    int e = n >> 11, r11 = n & 2047;
    int g = r11 >> 8;
    int rb = g * 8 + ((r11 >> 5) & 7);
    int cb = r11 & 31;
    if (rb * 128 >= padded_count[e]) return;
    int row0 = poffsets[e] + rb * 128;
    const u16* Arows = Xg + (size_t)row0 * 1024;
    const u16* Brows = W1c + (size_t)e * DFF * 1024 + (size_t)cb * 128 * 1024;
    f32x4 acc[4][4];
#pragma unroll
    for (int i = 0; i < 4; ++i)
#pragma unroll
        for (int j = 0; j < 4; ++j) { acc[i][j][0]=0.f; acc[i][j][1]=0.f; acc[i][j][2]=0.f; acc[i][j][3]=0.f; }
    gemm_main(Arows, 1024, Brows, 1024, 16, smem, acc);

    int tid = threadIdx.x;
    int l = tid & 63, lane16 = l & 15, hi = l >> 4;
    int wm = (tid >> 6) & 1, wn = tid >> 7;
    const float* b1e = b1 + (size_t)e * DFF;
#pragma unroll
    for (int mi = 0; mi < 4; ++mi) {
#pragma unroll
        for (int ni = 0; ni < 4; ++ni) {
            int col = cb * 128 + wn * 64 + ni * 16 + lane16;
            float bv = b1e[col];
#pragma unroll
            for (int r = 0; r < 4; ++r) {
                int grow = row0 + wm * 64 + mi * 16 + hi * 4 + r;
                float z = acc[mi][ni][r] + bv;
                float hval = z / (1.f + __expf(-z));
                H[(size_t)grow * DFF + col] = f2bf(hval);
            }
        }
    }
}

// ---------------- GEMM2: Og[row] = Hb @ W2c (bf16 out), K=4096 ----------------
// Region-ordered swizzled 1D grid: e (8) x group (4: 16 rb) x rb-in-group (16) x cb (8).
__global__ __launch_bounds__(256, 5) void gemm2_k(
    const u16* __restrict__ Hb, const u16* __restrict__ W2c,
    const int* __restrict__ padded_count, const int* __restrict__ poffsets,
    u16* __restrict__ Og)
{
    __shared__ char smem[32768];
    int n = blockIdx.x;
    int e = n >> 9, r9 = n & 511;
    int g = r9 >> 7;
    int rb = g * 16 + ((r9 >> 3) & 15);
    int cb = r9 & 7;
    if (rb * 128 >= padded_count[e]) return;
    int row0 = poffsets[e] + rb * 128;
    const u16* Arows = Hb + (size_t)row0 * DFF;
    const u16* Brows = W2c + (size_t)e * DM * DFF + (size_t)cb * 128 * DFF;
    f32x4 acc[4][4];
#pragma unroll
    for (int i = 0; i < 4; ++i)
#pragma unroll
        for (int j = 0; j < 4; ++j) { acc[i][j][0]=0.f; acc[i][j][1]=0.f; acc[i][j][2]=0.f; acc[i][j][3]=0.f; }
    gemm_main(Arows, DFF, Brows, DFF, 64, smem, acc);

    int tid = threadIdx.x;
    int l = tid & 63, lane16 = l & 15, hi = l >> 4;
    int wm = (tid >> 6) & 1, wn = tid >> 7;
#pragma unroll
    for (int mi = 0; mi < 4; ++mi) {
#pragma unroll
        for (int r = 0; r < 4; ++r) {
            int grow = row0 + wm * 64 + mi * 16 + hi * 4 + r;
            u16* orow = Og + (size_t)grow * DM;
#pragma unroll
            for (int ni = 0; ni < 4; ++ni) {
                int col = cb * 128 + wn * 64 + ni * 16 + lane16;
                orow[col] = f2bf(acc[mi][ni][r]);
            }
        }
    }
}

// ---------------- combine: out[t] = sum_r w_r * (Og[row_r] + b2[e_r]), Og bf16 ----------------
__global__ __launch_bounds__(256) void combine_k(
    const u16* __restrict__ Og, const float* __restrict__ b2,
    const int* __restrict__ tok_e, const int* __restrict__ tok_q, const float* __restrict__ tok_w,
    const int* __restrict__ poffsets, float* __restrict__ out)
{
    int t = blockIdx.x * 4 + (threadIdx.x >> 6);
    int l = threadIdx.x & 63;
    int e0 = tok_e[t * 2], q0 = tok_q[t * 2];
    int e1 = tok_e[t * 2 + 1], q1 = tok_q[t * 2 + 1];
    float w0 = tok_w[t * 2], w1 = tok_w[t * 2 + 1];
    const u16* r0 = Og + (size_t)(poffsets[e0] + q0) * DM;
    const u16* r1 = Og + (size_t)(poffsets[e1] + q1) * DM;
    const float* bb0 = b2 + (size_t)e0 * DM;
    const float* bb1 = b2 + (size_t)e1 * DM;
    float* o = out + (size_t)t * DM;
#pragma unroll
    for (int i = 0; i < 2; ++i) {
        int c = l * 8 + i * 512;
        uint4 a8 = *reinterpret_cast<const uint4*>(r0 + c);
        uint4 b8 = *reinterpret_cast<const uint4*>(r1 + c);
        const u32* au = &a8.x;
        const u32* bu = &b8.x;
        float4 res[2];
#pragma unroll
        for (int h = 0; h < 2; ++h) {
            float4 p = *reinterpret_cast<const float4*>(bb0 + c + h * 4);
            float4 q = *reinterpret_cast<const float4*>(bb1 + c + h * 4);
            float a0 = bf2f((u16)(au[h * 2] & 0xffff)),     a1 = bf2f((u16)(au[h * 2] >> 16));
            float a2 = bf2f((u16)(au[h * 2 + 1] & 0xffff)), a3 = bf2f((u16)(au[h * 2 + 1] >> 16));
            float c0 = bf2f((u16)(bu[h * 2] & 0xffff)),     c1 = bf2f((u16)(bu[h * 2] >> 16));
            float c2 = bf2f((u16)(bu[h * 2 + 1] & 0xffff)), c3 = bf2f((u16)(bu[h * 2 + 1] >> 16));
            res[h].x = w0 * (a0 + p.x) + w1 * (c0 + q.x);
            res[h].y = w0 * (a1 + p.y) + w1 * (c1 + q.y);
            res[h].z = w0 * (a2 + p.z) + w1 * (c2 + q.z);
            res[h].w = w0 * (a3 + p.w) + w1 * (c3 + q.w);
        }
        *reinterpret_cast<float4*>(o + c) = res[0];
        *reinterpret_cast<float4*>(o + c + 4) = res[1];
    }
}

extern "C" void kernel_launch(void* const* d_in, const int* in_sizes, int n_in,
                              void* d_out, int out_size, void* d_ws, size_t ws_size,
                              hipStream_t stream) {
    (void)in_sizes; (void)n_in; (void)out_size; (void)ws_size;
    const float* x  = (const float*)d_in[0];
    const float* Wr = (const float*)d_in[1];
    const float* br = (const float*)d_in[2];
    const float* W1 = (const float*)d_in[3];
    const float* b1 = (const float*)d_in[4];
    const float* W2 = (const float*)d_in[5];
    const float* b2 = (const float*)d_in[6];
    float* out = (float*)d_out;   // [8192*1024] out, then [1] aux

    char* ws = (char*)d_ws;
    int*   expert_count = (int*)(ws + 0);
    float* prob_sum     = (float*)(ws + 32);
    int*   padded_count = (int*)(ws + 64);
    int*   poffsets     = (int*)(ws + 96);
    int*   list_token   = (int*)(ws + 256);                 // 256 KiB
    float* list_w       = (float*)(ws + 256 + 262144);      // 256 KiB
    int*   tok_e        = (int*)(ws + 524544);              // 64 KiB
    int*   tok_q        = (int*)(ws + 524544 + 65536);      // 64 KiB
    float* tok_w        = (float*)(ws + 524544 + 131072);   // 64 KiB

    // Layout: HDR | Hb (144.7M) | W2c (67.1M) | Xg (36.2M) | W1c (67.1M);
    // Og (bf16, 36.2M) aliases Xg (dead after gemm1). Total ~316.1 MB.
    const size_t HDR    = 1048576;
    const size_t OFF_HB = HDR;
    const size_t OFF_W2 = OFF_HB + (size_t)MAXRA * DFF * 2;
    const size_t OFF_XG = OFF_W2 + (size_t)NE * DM * DFF * 2;
    const size_t OFF_W1 = OFF_XG + (size_t)MAXRA * DM * 2;
    u16*   Hb  = (u16*)(ws + OFF_HB);
    u16*   W2c = (u16*)(ws + OFF_W2);
    u16*   Xg  = (u16*)(ws + OFF_XG);
    u16*   W1c = (u16*)(ws + OFF_W1);
    u16*   Og  = (u16*)(ws + OFF_XG);

    hipMemsetAsync(ws, 0, 64, stream);
    router_k<<<TT / RTOK, 256, 0, stream>>>(x, Wr, br, expert_count, prob_sum, list_token, list_w,
                                            tok_e, tok_q, tok_w);
    scan_aux_k<<<1, 64, 0, stream>>>(expert_count, prob_sum, padded_count, poffsets,
                                     out + (size_t)TT * DM);
    gather_k<<<dim3(1024, 8), 256, 0, stream>>>(x, list_token, expert_count, padded_count, poffsets, Xg);

    // W1[e][k<1024][j<4096] -> W1c[e][j][k] ; W2[e][k<4096][j<1024] -> W2c[e][j][k]
    convt_k<<<dim3(16, 64, 8), 256, 0, stream>>>(W1, W1c, DFF, 1024, (long)DM * DFF);
    convt_k<<<dim3(64, 16, 8), 256, 0, stream>>>(W2, W2c, DM, 4096, (long)DM * DFF);

    gemm1_k<<<16384, 256, 0, stream>>>(Xg, W1c, b1, padded_count, poffsets, Hb);
    gemm2_k<<<4096, 256, 0, stream>>>(Hb, W2c, padded_count, poffsets, Og);
    combine_k<<<TT / 4, 256, 0, stream>>>(Og, b2, tok_e, tok_q, tok_w, poffsets, out);
}

// Round 12
// 526.505 us; speedup vs baseline: 1.9819x; 1.9819x over previous
//
#include <hip/hip_runtime.h>

#define DM     1024
#define DFF    4096
#define NE     8
#define TT     8192
#define CAP    8192
#define RTOK   32
#define MAXRA  17664

typedef __bf16 bf16x8 __attribute__((ext_vector_type(8)));
typedef float  f32x4  __attribute__((ext_vector_type(4)));
typedef unsigned short u16;
typedef unsigned int   u32;

__device__ __forceinline__ u16 f2bf(float f) {
    u32 u = __builtin_bit_cast(u32, f);
    u += 0x7fffu + ((u >> 16) & 1u);   // round-to-nearest-even
    return (u16)(u >> 16);
}

__device__ __forceinline__ float bf2f(u16 h) {
    u32 u = ((u32)h) << 16;
    return __builtin_bit_cast(float, u);
}

__device__ __forceinline__ void gload_lds16(const void* g, void* l) {
    __builtin_amdgcn_global_load_lds(
        (const __attribute__((address_space(1))) void*)g,
        (__attribute__((address_space(3))) void*)l,
        16, 0, 0);
}

// ---------------- router: block-aggregated top-2 routing ----------------
__global__ __launch_bounds__(256) void router_k(
    const float* __restrict__ x, const float* __restrict__ Wr, const float* __restrict__ br,
    int* __restrict__ expert_count, float* __restrict__ prob_sum,
    int* __restrict__ list_token, float* __restrict__ list_w,
    int* __restrict__ tok_e, int* __restrict__ tok_q, float* __restrict__ tok_w)
{
    __shared__ float wrT[NE][DM];
    __shared__ float ps[NE];
    __shared__ int   lcount[NE];
    __shared__ int   lbase[NE];
    __shared__ int   lexp[RTOK * 2];
    __shared__ float lw[RTOK * 2];
    __shared__ int   lslot[RTOK * 2];

    int tid = threadIdx.x;
    if (tid < NE) { ps[tid] = 0.f; lcount[tid] = 0; }
#pragma unroll
    for (int it = 0; it < 8; ++it) {
        int f = tid * 4 + it * 1024;
        float4 v = *reinterpret_cast<const float4*>(Wr + f);
        int e0 = f & 7, k = f >> 3;
        wrT[e0][k] = v.x; wrT[e0 + 1][k] = v.y; wrT[e0 + 2][k] = v.z; wrT[e0 + 3][k] = v.w;
    }
    __syncthreads();

    int w = tid >> 6, l = tid & 63;
    for (int j = 0; j < RTOK / 4; ++j) {
        int ti = w * (RTOK / 4) + j;
        int token = blockIdx.x * RTOK + ti;
        const float* xr = x + (size_t)token * DM;
        float acc[NE];
#pragma unroll
        for (int e = 0; e < NE; ++e) acc[e] = 0.f;
#pragma unroll
        for (int i = 0; i < 4; ++i) {
            float4 xv = *reinterpret_cast<const float4*>(xr + i * 256 + l * 4);
#pragma unroll
            for (int e = 0; e < NE; ++e) {
                float4 wv = *reinterpret_cast<const float4*>(&wrT[e][i * 256 + l * 4]);
                acc[e] += xv.x * wv.x + xv.y * wv.y + xv.z * wv.z + xv.w * wv.w;
            }
        }
#pragma unroll
        for (int off = 32; off >= 1; off >>= 1) {
#pragma unroll
            for (int e = 0; e < NE; ++e) acc[e] += __shfl_xor(acc[e], off);
        }
        if (l == 0) {
            float li[NE], m = -1e30f;
#pragma unroll
            for (int e = 0; e < NE; ++e) { li[e] = (acc[e] + br[e]) * (1.0f / 0.7f); m = fmaxf(m, li[e]); }
            float p[NE], s = 0.f;
#pragma unroll
            for (int e = 0; e < NE; ++e) { p[e] = __expf(li[e] - m); s += p[e]; }
            float inv = 1.f / s;
#pragma unroll
            for (int e = 0; e < NE; ++e) { p[e] *= inv; atomicAdd(&ps[e], p[e]); }
            float v1 = -1.f, v2 = -1.f; int e1 = 0, e2 = 0;
#pragma unroll
            for (int e = 0; e < NE; ++e) {   // ascending scan: ties keep lower index (top_k semantics)
                float pe = p[e];
                if (pe > v1)      { v2 = v1; e2 = e1; v1 = pe; e1 = e; }
                else if (pe > v2) { v2 = pe; e2 = e; }
            }
            float denom = v1 + v2 + 1e-6f;
            lexp[2 * ti]     = e1; lw[2 * ti]     = v1 / denom; lslot[2 * ti]     = atomicAdd(&lcount[e1], 1);
            lexp[2 * ti + 1] = e2; lw[2 * ti + 1] = v2 / denom; lslot[2 * ti + 1] = atomicAdd(&lcount[e2], 1);
        }
    }
    __syncthreads();
    if (tid < NE) {
        lbase[tid] = atomicAdd(&expert_count[tid], lcount[tid]);
        atomicAdd(&prob_sum[tid], ps[tid]);
    }
    __syncthreads();
    if (tid < RTOK * 2) {
        int e = lexp[tid];
        int q = lbase[e] + lslot[tid];
        int token = blockIdx.x * RTOK + (tid >> 1);
        list_token[e * CAP + q] = token;
        list_w[e * CAP + q] = lw[tid];
        int slot = token * 2 + (tid & 1);
        tok_e[slot] = e; tok_q[slot] = q; tok_w[slot] = lw[tid];
    }
}

// ---------------- scan: padded offsets (to 128) + aux loss ----------------
__global__ void scan_aux_k(const int* __restrict__ expert_count, const float* __restrict__ prob_sum,
                           int* __restrict__ padded_count, int* __restrict__ poffsets,
                           float* __restrict__ aux_out)
{
    if (threadIdx.x == 0 && blockIdx.x == 0) {
        int off = 0; float aux = 0.f;
        for (int e = 0; e < NE; ++e) {
            int c = expert_count[e];
            int pc = (c + 127) / 128 * 128;
            poffsets[e] = off; padded_count[e] = pc; off += pc;
            aux += ((float)c / (float)TT) * (prob_sum[e] / (float)TT);
        }
        aux_out[0] = aux * (float)NE;
    }
}

// ---------------- gather routed x rows -> bf16 Xg ----------------
__global__ __launch_bounds__(256) void gather_k(
    const float* __restrict__ x, const int* __restrict__ list_token,
    const int* __restrict__ expert_count, const int* __restrict__ padded_count,
    const int* __restrict__ poffsets, u16* __restrict__ Xg)
{
    int e = blockIdx.y;
    int p0 = blockIdx.x * 8;
    if (p0 >= padded_count[e]) return;
    int tid = threadIdx.x;
    int rr = tid >> 5, cl = tid & 31;
    int p = p0 + rr;
    int g = poffsets[e] + p;
    u16* dst = Xg + (size_t)g * DM;
    bool valid = p < expert_count[e];
    int tok = valid ? list_token[e * CAP + p] : 0;
    const float* src = x + (size_t)tok * DM;
#pragma unroll
    for (int i = 0; i < 4; ++i) {
        int c0 = cl * 8 + i * 256;
        uint4 v;
        if (valid) {
            float4 f0 = *reinterpret_cast<const float4*>(src + c0);
            float4 f1 = *reinterpret_cast<const float4*>(src + c0 + 4);
            v.x = f2bf(f0.x) | ((u32)f2bf(f0.y) << 16);
            v.y = f2bf(f0.z) | ((u32)f2bf(f0.w) << 16);
            v.z = f2bf(f1.x) | ((u32)f2bf(f1.y) << 16);
            v.w = f2bf(f1.z) | ((u32)f2bf(f1.w) << 16);
        } else {
            v.x = 0; v.y = 0; v.z = 0; v.w = 0;
        }
        *reinterpret_cast<uint4*>(dst + c0) = v;
    }
}

// ---------------- transpose + fp32->bf16: src[e][k*rs + j] -> dst[e][j*Ktot + k] ----------------
__global__ __launch_bounds__(256) void convt_k(
    const float* __restrict__ src, u16* __restrict__ dst, int rs, int Ktot, long dstEStride)
{
    __shared__ float tile[64][65];
    int e = blockIdx.z;
    int k0 = blockIdx.x * 64, j0 = blockIdx.y * 64;
    const float* s = src + (size_t)e * 4194304;
    int tid = threadIdx.x;
    {
        int jj = (tid & 15) * 4, kb = tid >> 4;
#pragma unroll
        for (int i = 0; i < 4; ++i) {
            int k = kb + i * 16;
            float4 v = *reinterpret_cast<const float4*>(s + (size_t)(k0 + k) * rs + j0 + jj);
            tile[k][jj] = v.x; tile[k][jj + 1] = v.y; tile[k][jj + 2] = v.z; tile[k][jj + 3] = v.w;
        }
    }
    __syncthreads();
    {
        int kk = (tid & 15) * 4, jb = tid >> 4;
        u16* d = dst + (size_t)e * dstEStride;
#pragma unroll
        for (int i = 0; i < 4; ++i) {
            int j = jb + i * 16;
            uint2 q;
            q.x = f2bf(tile[kk][j])     | ((u32)f2bf(tile[kk + 1][j]) << 16);
            q.y = f2bf(tile[kk + 2][j]) | ((u32)f2bf(tile[kk + 3][j]) << 16);
            *reinterpret_cast<uint2*>(d + (size_t)(j0 + j) * Ktot + k0 + kk) = q;
        }
    }
}

// ---------------- PROVEN 128x128 bf16 GEMM mainloop (single-buffer, gload_lds, 256 thr) ----------------
// 16B chunk slot = row*8 + (c8 ^ (row&7)); staged linearly via pre-swizzled global source
// (both-sides involution; 0 bank conflicts measured R2-R10). m97-class structure:
// gemm1 ~762 TF / gemm2 ~653 TF — at this structure's proven shape-ceiling (m102/m112).
// NOTE (R11 lesson): do NOT raise launch_bounds to (256,5) — it caps VGPRs below the
// acc's needs and spills to scratch (WRITE_SIZE 135->737 MB, dur 2.3x worse).
__device__ __forceinline__ void stage_tile(const u16* __restrict__ rows, long lda, int kt, char* buf) {
    int tid = threadIdx.x;
    int w = tid >> 6, l = tid & 63;
#pragma unroll
    for (int i = 0; i < 4; ++i) {
        int sbase = i * 256 + w * 64;       // wave-uniform LDS slot base
        int sl = sbase + l;
        int row = sl >> 3;
        int c8 = (sl & 7) ^ (row & 7);
        const u16* src = rows + (size_t)row * lda + kt * 64 + c8 * 8;
        gload_lds16(src, buf + sbase * 16);
    }
}

__device__ __forceinline__ void gemm_main(
    const u16* __restrict__ Arows, long lda,
    const u16* __restrict__ Brows, long ldb,
    int nkt, char* smem, f32x4 acc[4][4])
{
    int tid = threadIdx.x;
    int l = tid & 63, lane16 = l & 15, hi = l >> 4;
    int wm = (tid >> 6) & 1, wn = tid >> 7;

    for (int kt = 0; kt < nkt; ++kt) {
        stage_tile(Arows, lda, kt, smem);
        stage_tile(Brows, ldb, kt, smem + 16384);
        __syncthreads();
        const char* bufA = smem;
        const char* bufB = smem + 16384;
#pragma unroll
        for (int kk = 0; kk < 2; ++kk) {
            bf16x8 af[4], bb[4];
#pragma unroll
            for (int mi = 0; mi < 4; ++mi) {
                int row = wm * 64 + mi * 16 + lane16;
                int ch = (kk * 4 + hi) ^ (row & 7);
                af[mi] = *reinterpret_cast<const bf16x8*>(bufA + (row * 8 + ch) * 16);
            }
#pragma unroll
            for (int ni = 0; ni < 4; ++ni) {
                int row = wn * 64 + ni * 16 + lane16;
                int ch = (kk * 4 + hi) ^ (row & 7);
                bb[ni] = *reinterpret_cast<const bf16x8*>(bufB + (row * 8 + ch) * 16);
            }
#pragma unroll
            for (int mi = 0; mi < 4; ++mi)
#pragma unroll
                for (int ni = 0; ni < 4; ++ni)
                    acc[mi][ni] = __builtin_amdgcn_mfma_f32_16x16x32_bf16(af[mi], bb[ni], acc[mi][ni], 0, 0, 0);
        }
        __syncthreads();
    }
}

// ---------------- GEMM1: H = silu(Xg @ W1c + b1), bf16, N=4096, K=1024 ----------------
// Region-ordered swizzled 1D grid: e (8) x group (8: 8 rb) x rb-in-group (8) x cb (32).
__global__ __launch_bounds__(256, 4) void gemm1_k(
    const u16* __restrict__ Xg, const u16* __restrict__ W1c, const float* __restrict__ b1,
    const int* __restrict__ padded_count, const int* __restrict__ poffsets,
    u16* __restrict__ H)
{
    __shared__ char smem[32768];
    int n = blockIdx.x;
    int e = n >> 11, r11 = n & 2047;
    int g = r11 >> 8;
    int rb = g * 8 + ((r11 >> 5) & 7);
    int cb = r11 & 31;
    if (rb * 128 >= padded_count[e]) return;
    int row0 = poffsets[e] + rb * 128;
    const u16* Arows = Xg + (size_t)row0 * 1024;
    const u16* Brows = W1c + (size_t)e * DFF * 1024 + (size_t)cb * 128 * 1024;
    f32x4 acc[4][4];
#pragma unroll
    for (int i = 0; i < 4; ++i)
#pragma unroll
        for (int j = 0; j < 4; ++j) { acc[i][j][0]=0.f; acc[i][j][1]=0.f; acc[i][j][2]=0.f; acc[i][j][3]=0.f; }
    gemm_main(Arows, 1024, Brows, 1024, 16, smem, acc);

    int tid = threadIdx.x;
    int l = tid & 63, lane16 = l & 15, hi = l >> 4;
    int wm = (tid >> 6) & 1, wn = tid >> 7;
    const float* b1e = b1 + (size_t)e * DFF;
#pragma unroll
    for (int mi = 0; mi < 4; ++mi) {
#pragma unroll
        for (int ni = 0; ni < 4; ++ni) {
            int col = cb * 128 + wn * 64 + ni * 16 + lane16;
            float bv = b1e[col];
#pragma unroll
            for (int r = 0; r < 4; ++r) {
                int grow = row0 + wm * 64 + mi * 16 + hi * 4 + r;
                float z = acc[mi][ni][r] + bv;
                float hval = z / (1.f + __expf(-z));
                H[(size_t)grow * DFF + col] = f2bf(hval);
            }
        }
    }
}

// ---------------- GEMM2: Og[row] = Hb @ W2c (bf16 out), K=4096 ----------------
// Region-ordered swizzled 1D grid: e (8) x group (4: 16 rb) x rb-in-group (16) x cb (8).
__global__ __launch_bounds__(256, 4) void gemm2_k(
    const u16* __restrict__ Hb, const u16* __restrict__ W2c,
    const int* __restrict__ padded_count, const int* __restrict__ poffsets,
    u16* __restrict__ Og)
{
    __shared__ char smem[32768];
    int n = blockIdx.x;
    int e = n >> 9, r9 = n & 511;
    int g = r9 >> 7;
    int rb = g * 16 + ((r9 >> 3) & 15);
    int cb = r9 & 7;
    if (rb * 128 >= padded_count[e]) return;
    int row0 = poffsets[e] + rb * 128;
    const u16* Arows = Hb + (size_t)row0 * DFF;
    const u16* Brows = W2c + (size_t)e * DM * DFF + (size_t)cb * 128 * DFF;
    f32x4 acc[4][4];
#pragma unroll
    for (int i = 0; i < 4; ++i)
#pragma unroll
        for (int j = 0; j < 4; ++j) { acc[i][j][0]=0.f; acc[i][j][1]=0.f; acc[i][j][2]=0.f; acc[i][j][3]=0.f; }
    gemm_main(Arows, DFF, Brows, DFF, 64, smem, acc);

    int tid = threadIdx.x;
    int l = tid & 63, lane16 = l & 15, hi = l >> 4;
    int wm = (tid >> 6) & 1, wn = tid >> 7;
#pragma unroll
    for (int mi = 0; mi < 4; ++mi) {
#pragma unroll
        for (int r = 0; r < 4; ++r) {
            int grow = row0 + wm * 64 + mi * 16 + hi * 4 + r;
            u16* orow = Og + (size_t)grow * DM;
#pragma unroll
            for (int ni = 0; ni < 4; ++ni) {
                int col = cb * 128 + wn * 64 + ni * 16 + lane16;
                orow[col] = f2bf(acc[mi][ni][r]);
            }
        }
    }
}

// ---------------- combine: out[t] = sum_r w_r * (Og[row_r] + b2[e_r]), Og bf16 ----------------
__global__ __launch_bounds__(256) void combine_k(
    const u16* __restrict__ Og, const float* __restrict__ b2,
    const int* __restrict__ tok_e, const int* __restrict__ tok_q, const float* __restrict__ tok_w,
    const int* __restrict__ poffsets, float* __restrict__ out)
{
    int t = blockIdx.x * 4 + (threadIdx.x >> 6);
    int l = threadIdx.x & 63;
    int e0 = tok_e[t * 2], q0 = tok_q[t * 2];
    int e1 = tok_e[t * 2 + 1], q1 = tok_q[t * 2 + 1];
    float w0 = tok_w[t * 2], w1 = tok_w[t * 2 + 1];
    const u16* r0 = Og + (size_t)(poffsets[e0] + q0) * DM;
    const u16* r1 = Og + (size_t)(poffsets[e1] + q1) * DM;
    const float* bb0 = b2 + (size_t)e0 * DM;
    const float* bb1 = b2 + (size_t)e1 * DM;
    float* o = out + (size_t)t * DM;
#pragma unroll
    for (int i = 0; i < 2; ++i) {
        int c = l * 8 + i * 512;
        uint4 a8 = *reinterpret_cast<const uint4*>(r0 + c);
        uint4 b8 = *reinterpret_cast<const uint4*>(r1 + c);
        const u32* au = &a8.x;
        const u32* bu = &b8.x;
        float4 res[2];
#pragma unroll
        for (int h = 0; h < 2; ++h) {
            float4 p = *reinterpret_cast<const float4*>(bb0 + c + h * 4);
            float4 q = *reinterpret_cast<const float4*>(bb1 + c + h * 4);
            float a0 = bf2f((u16)(au[h * 2] & 0xffff)),     a1 = bf2f((u16)(au[h * 2] >> 16));
            float a2 = bf2f((u16)(au[h * 2 + 1] & 0xffff)), a3 = bf2f((u16)(au[h * 2 + 1] >> 16));
            float c0 = bf2f((u16)(bu[h * 2] & 0xffff)),     c1 = bf2f((u16)(bu[h * 2] >> 16));
            float c2 = bf2f((u16)(bu[h * 2 + 1] & 0xffff)), c3 = bf2f((u16)(bu[h * 2 + 1] >> 16));
            res[h].x = w0 * (a0 + p.x) + w1 * (c0 + q.x);
            res[h].y = w0 * (a1 + p.y) + w1 * (c1 + q.y);
            res[h].z = w0 * (a2 + p.z) + w1 * (c2 + q.z);
            res[h].w = w0 * (a3 + p.w) + w1 * (c3 + q.w);
        }
        *reinterpret_cast<float4*>(o + c) = res[0];
        *reinterpret_cast<float4*>(o + c + 4) = res[1];
    }
}

extern "C" void kernel_launch(void* const* d_in, const int* in_sizes, int n_in,
                              void* d_out, int out_size, void* d_ws, size_t ws_size,
                              hipStream_t stream) {
    (void)in_sizes; (void)n_in; (void)out_size; (void)ws_size;
    const float* x  = (const float*)d_in[0];
    const float* Wr = (const float*)d_in[1];
    const float* br = (const float*)d_in[2];
    const float* W1 = (const float*)d_in[3];
    const float* b1 = (const float*)d_in[4];
    const float* W2 = (const float*)d_in[5];
    const float* b2 = (const float*)d_in[6];
    float* out = (float*)d_out;   // [8192*1024] out, then [1] aux

    char* ws = (char*)d_ws;
    int*   expert_count = (int*)(ws + 0);
    float* prob_sum     = (float*)(ws + 32);
    int*   padded_count = (int*)(ws + 64);
    int*   poffsets     = (int*)(ws + 96);
    int*   list_token   = (int*)(ws + 256);                 // 256 KiB
    float* list_w       = (float*)(ws + 256 + 262144);      // 256 KiB
    int*   tok_e        = (int*)(ws + 524544);              // 64 KiB
    int*   tok_q        = (int*)(ws + 524544 + 65536);      // 64 KiB
    float* tok_w        = (float*)(ws + 524544 + 131072);   // 64 KiB

    // Layout: HDR | Hb (144.7M) | W2c (67.1M) | Xg (36.2M) | W1c (67.1M);
    // Og (bf16, 36.2M) aliases Xg (dead after gemm1). Total ~316.1 MB.
    const size_t HDR    = 1048576;
    const size_t OFF_HB = HDR;
    const size_t OFF_W2 = OFF_HB + (size_t)MAXRA * DFF * 2;
    const size_t OFF_XG = OFF_W2 + (size_t)NE * DM * DFF * 2;
    const size_t OFF_W1 = OFF_XG + (size_t)MAXRA * DM * 2;
    u16*   Hb  = (u16*)(ws + OFF_HB);
    u16*   W2c = (u16*)(ws + OFF_W2);
    u16*   Xg  = (u16*)(ws + OFF_XG);
    u16*   W1c = (u16*)(ws + OFF_W1);
    u16*   Og  = (u16*)(ws + OFF_XG);

    hipMemsetAsync(ws, 0, 64, stream);
    router_k<<<TT / RTOK, 256, 0, stream>>>(x, Wr, br, expert_count, prob_sum, list_token, list_w,
                                            tok_e, tok_q, tok_w);
    scan_aux_k<<<1, 64, 0, stream>>>(expert_count, prob_sum, padded_count, poffsets,
                                     out + (size_t)TT * DM);
    gather_k<<<dim3(1024, 8), 256, 0, stream>>>(x, list_token, expert_count, padded_count, poffsets, Xg);

    // W1[e][k<1024][j<4096] -> W1c[e][j][k] ; W2[e][k<4096][j<1024] -> W2c[e][j][k]
    convt_k<<<dim3(16, 64, 8), 256, 0, stream>>>(W1, W1c, DFF, 1024, (long)DM * DFF);
    convt_k<<<dim3(64, 16, 8), 256, 0, stream>>>(W2, W2c, DM, 4096, (long)DM * DFF);

    gemm1_k<<<16384, 256, 0, stream>>>(Xg, W1c, b1, padded_count, poffsets, Hb);
    gemm2_k<<<4096, 256, 0, stream>>>(Hb, W2c, padded_count, poffsets, Og);
    combine_k<<<TT / 4, 256, 0, stream>>>(Og, b2, tok_e, tok_q, tok_w, poffsets, out);
}